// Round 1
// baseline (23.077 us; speedup 1.0000x reference)
//
#include <hip/hip_runtime.h>
#include <hip/hip_bf16.h>

// Shapes: x,gn (8,128,64) f32; fb (1,128,32768) f32; resonance (64,128) f32.
// out (8,1,32768) f32.
// r[b,c,f] = sum_rr softmax(x+gn)[b,c,rr] * res[rr,f]
// out[b,s] = (1/128) * sum_c lerp(r[b,c,:], s) * fb[c,s]

#define BATCH 8
#define BANDS 128
#define RES 64
#define NF 128
#define NS 32768

// ---------------- Kernel A: softmax + matvec -> rT[f][b*128+c] ----------------
__global__ __launch_bounds__(64) void kA(const float* __restrict__ x,
                                         const float* __restrict__ gn,
                                         const float* __restrict__ res,
                                         float* __restrict__ rT) {
    const int bc = blockIdx.x;        // b*128 + c, 0..1023
    const int t  = threadIdx.x;       // 0..63 (one full wave)

    float v = x[bc * RES + t] + gn[bc * RES + t];

    // wave-wide max (64 lanes)
    float m = v;
    #pragma unroll
    for (int off = 32; off > 0; off >>= 1)
        m = fmaxf(m, __shfl_xor(m, off));
    float e = expf(v - m);
    float ssum = e;
    #pragma unroll
    for (int off = 32; off > 0; off >>= 1)
        ssum += __shfl_xor(ssum, off);
    float g = e / ssum;

    __shared__ float gs[RES];
    gs[t] = g;
    __syncthreads();

    // each thread computes frames f=t and f=t+64
    float r0 = 0.f, r1 = 0.f;
    #pragma unroll 4
    for (int rr = 0; rr < RES; ++rr) {
        float gg = gs[rr];
        r0 = fmaf(gg, res[rr * NF + t], r0);
        r1 = fmaf(gg, res[rr * NF + t + 64], r1);
    }
    rT[t * (BATCH * BANDS) + bc]        = r0;
    rT[(t + 64) * (BATCH * BANDS) + bc] = r1;
}

// ---------------- Kernel B: interp + fb multiply + band mean ----------------
// Block k handles samples [256k, 256k+255]. lo(s) = floor((s-127.5)/256) in
// {k-1, k} (after clip), wave-uniform. Stage frames {k-1,k,k+1} (clamped).
__global__ __launch_bounds__(256) void kB(const float* __restrict__ fb,
                                          const float* __restrict__ rT,
                                          float* __restrict__ out) {
    const int k   = blockIdx.x;       // 0..127
    const int tid = threadIdx.x;      // 0..255

    __shared__ float fr[3][BATCH * BANDS];
    __shared__ float dd[2][BATCH * BANDS];

    const int fbase = k - 1;
    for (int i = tid; i < 3 * BATCH * BANDS; i += 256) {
        int j = i >> 10, idx = i & 1023;
        int f = min(max(fbase + j, 0), NF - 1);
        fr[j][idx] = rT[f * (BATCH * BANDS) + idx];
    }
    __syncthreads();
    for (int i = tid; i < 2 * BATCH * BANDS; i += 256) {
        int j = i >> 10, idx = i & 1023;
        dd[j][idx] = fr[j + 1][idx] - fr[j][idx];
    }
    __syncthreads();

    const int s = k * 256 + tid;
    float pos = (s + 0.5f) * (1.0f / 256.0f) - 0.5f;
    pos = fminf(fmaxf(pos, 0.0f), (float)(NF - 1));
    const int lo = (int)floorf(pos);
    const float w = pos - (float)lo;
    const int il = lo - fbase;        // in {0,1}; il+1 <= 2

    const float* __restrict__ frp = &fr[il][0];
    const float* __restrict__ ddp = &dd[il][0];

    float acc[BATCH];
    #pragma unroll
    for (int b = 0; b < BATCH; ++b) acc[b] = 0.f;

    for (int c = 0; c < BANDS; c += 4) {
        const float f0 = fb[(c + 0) * NS + s];
        const float f1 = fb[(c + 1) * NS + s];
        const float f2 = fb[(c + 2) * NS + s];
        const float f3 = fb[(c + 3) * NS + s];
        #pragma unroll
        for (int b = 0; b < BATCH; ++b) {
            const float4 rl = *(const float4*)&frp[b * BANDS + c];
            const float4 dl = *(const float4*)&ddp[b * BANDS + c];
            acc[b] = fmaf(f0, fmaf(w, dl.x, rl.x), acc[b]);
            acc[b] = fmaf(f1, fmaf(w, dl.y, rl.y), acc[b]);
            acc[b] = fmaf(f2, fmaf(w, dl.z, rl.z), acc[b]);
            acc[b] = fmaf(f3, fmaf(w, dl.w, rl.w), acc[b]);
        }
    }

    #pragma unroll
    for (int b = 0; b < BATCH; ++b)
        out[b * NS + s] = acc[b] * (1.0f / (float)BANDS);
}

extern "C" void kernel_launch(void* const* d_in, const int* in_sizes, int n_in,
                              void* d_out, int out_size, void* d_ws, size_t ws_size,
                              hipStream_t stream) {
    const float* x   = (const float*)d_in[0];
    const float* gn  = (const float*)d_in[1];
    const float* fb  = (const float*)d_in[2];
    const float* res = (const float*)d_in[3];
    float* out = (float*)d_out;
    float* rT  = (float*)d_ws;   // NF * BATCH * BANDS floats = 512 KB

    kA<<<BATCH * BANDS, 64, 0, stream>>>(x, gn, res, rT);
    kB<<<NS / 256, 256, 0, stream>>>(fb, rT, out);
}